// Round 8
// baseline (2529.378 us; speedup 1.0000x reference)
//
#include <hip/hip_runtime.h>

typedef _Float16 half8 __attribute__((ext_vector_type(8)));
typedef float floatx4 __attribute__((ext_vector_type(4)));
typedef unsigned short ushort_t;

#define D 64
#define SSEG 120
#define NSTEP 600
#define NROW 601
#define BATCH 512
#define TPB 128

#define CVT16(v) __builtin_bit_cast(ushort_t, (_Float16)(v))

static __device__ __forceinline__ floatx4 mfma16(half8 a, half8 b, floatx4 c) {
  return __builtin_amdgcn_mfma_f32_16x16x32_f16(a, b, c, 0, 0, 0);
}
// LDS-only barrier (R4/R5-proven): order LDS without draining vmcnt.
static __device__ __forceinline__ void bar_lds() {
  __builtin_amdgcn_sched_barrier(0);
  asm volatile("s_waitcnt lgkmcnt(0)" ::: "memory");
  __builtin_amdgcn_s_barrier();
  __builtin_amdgcn_sched_barrier(0);
}

// One block = one trajectory, TWO waves (512 blocks x 128 thr -> 2 blocks/CU,
// two overlapping latency chains per CU — the R5 property that M=2 lost).
// Wave w owns h-cols [64w, 64w+64) for L1/L2 (4 N-tiles, 16 MFMA) and
// k-cols [32w, 32w+32) for L3 (2 tiles). M=1 dup-row A-frags (R5-verified):
// C col = lane&15, rows duplicated -> reg 0 valid in every lane; state is
// 16-lane periodic (elems d0=32w+c, d1=d0+16 per lane), epilogues unmasked,
// LDS/global writes masked to lane<16.
// Critical-path trim: stage-x partial sums (p3..p6, py) pre-accumulated at
// the top of the following stage (hidden under L1 read latency); epilogue
// on the KS->Xb path is 1 FMA + cvt + 4 b16 writes.
extern "C" __global__ void __launch_bounds__(TPB, 1)
NeuralDDEWithTime_46823733461186_kernel(
    const float* __restrict__ gts, const float* __restrict__ gy0,
    const float* __restrict__ gW1, const float* __restrict__ gb1,
    const float* __restrict__ gW2, const float* __restrict__ gb2,
    const float* __restrict__ gW3, const float* __restrict__ gb3,
    float* __restrict__ gout) {
  __shared__ half8 Xb[16];  // 128 halfs: [0..64)=y, [64..128)=hist
  __shared__ half8 Hb[16];  // h1
  __shared__ half8 Gb[16];  // h2

  const int tid = threadIdx.x;
  const int lane = tid & 63;
  const int w = tid >> 6;        // wave 0..1
  const int c = lane & 15;
  const int kg = lane >> 4;
  const bool wr = (lane < 16);

  const float ts0 = gts[0];
  const float dt = gts[1] - gts[0];

  // ---- weights -> VGPR B-frags (natural k order; one-time) ----
  half8 w1b[4][4], w2b[4][4], w3b[2][4];
  float b1t[4], w1tt[4], b2t[4], b3r[2];
#pragma unroll
  for (int t = 0; t < 4; ++t) {
    const int n = 64 * w + 16 * t + c;
#pragma unroll
    for (int ks = 0; ks < 4; ++ks) {
      const float* p1 = gW1 + n * 129 + ks * 32 + kg * 8;
      const float* p2 = gW2 + n * 128 + ks * 32 + kg * 8;
      half8 v1, v2;
#pragma unroll
      for (int e = 0; e < 8; ++e) { v1[e] = (_Float16)p1[e]; v2[e] = (_Float16)p2[e]; }
      w1b[t][ks] = v1; w2b[t][ks] = v2;
    }
    b1t[t] = gb1[n];
    w1tt[t] = gW1[n * 129 + 128];
    b2t[t] = gb2[n];
  }
#pragma unroll
  for (int t = 0; t < 2; ++t) {
    const int n = 32 * w + 16 * t + c;
#pragma unroll
    for (int ks = 0; ks < 4; ++ks) {
      const float* p3 = gW3 + n * 128 + ks * 32 + kg * 8;
      half8 v3;
#pragma unroll
      for (int e = 0; e < 8; ++e) v3[e] = (_Float16)p3[e];
      w3b[t][ks] = v3;
    }
    b3r[t] = gb3[n];
  }

  const int d0 = 32 * w + c, d1 = d0 + 16;   // this lane's 2 state elems
  const size_t obt = (size_t)blockIdx.x * (NROW * D);
  const float* gme0 = gout + obt + d0;
  const float* gme1 = gout + obt + d1;

  float y0v0 = gy0[blockIdx.x * D + d0];
  float y0v1 = gy0[blockIdx.x * D + d1];
  float y_0 = y0v0, y_1 = y0v1;
  float yp00 = y0v0, yp10 = y0v0, yp01 = y0v1, yp11 = y0v1;
  float np00 = 0.f, np10 = 0.f, np01 = 0.f, np11 = 0.f;
  float kp0, kp1;                              // previous stage's k
  float p30, p31, p40, p41, p50, p51, p60, p61, py0, py1;  // rolling partials

  if (wr) {
    gout[obt + d0] = y0v0;                    // dense row 0 = y0
    gout[obt + d1] = y0v1;
    ushort_t* xh = (ushort_t*)Xb;
    xh[d0] = CVT16(y0v0); xh[d1] = CVT16(y0v1);
    xh[D + d0] = CVT16(y0v0); xh[D + d1] = CVT16(y0v1);
  }
  if (blockIdx.x == 0 && tid == 0) gout[(size_t)BATCH * NROW * D] = 600.0f;  // num_steps
  bar_lds();

  const floatx4 zero4 = {0.f, 0.f, 0.f, 0.f};
  static const float ZV4[4] = {0.f, 0.f, 0.f, 0.f};

  // 128-out layer: OUT = relu(W*IN + b [+ w1t*t]); 4 tiles, depth-4 chains.
#define L128(WB, BT, TV, TS, IN, OUT)                                         \
  {                                                                           \
    const half8* xp = (const half8*)(IN) + kg;                                \
    half8 a0 = xp[0], a1 = xp[4], a2 = xp[8], a3 = xp[12];                    \
    __builtin_amdgcn_s_setprio(1);                                            \
    floatx4 q0 = mfma16(a0, WB[0][0], zero4);                                 \
    floatx4 q1 = mfma16(a0, WB[1][0], zero4);                                 \
    floatx4 q2 = mfma16(a0, WB[2][0], zero4);                                 \
    floatx4 q3 = mfma16(a0, WB[3][0], zero4);                                 \
    q0 = mfma16(a1, WB[0][1], q0); q1 = mfma16(a1, WB[1][1], q1);             \
    q2 = mfma16(a1, WB[2][1], q2); q3 = mfma16(a1, WB[3][1], q3);             \
    q0 = mfma16(a2, WB[0][2], q0); q1 = mfma16(a2, WB[1][2], q1);             \
    q2 = mfma16(a2, WB[2][2], q2); q3 = mfma16(a2, WB[3][2], q3);             \
    q0 = mfma16(a3, WB[0][3], q0); q1 = mfma16(a3, WB[1][3], q1);             \
    q2 = mfma16(a3, WB[2][3], q2); q3 = mfma16(a3, WB[3][3], q3);             \
    __builtin_amdgcn_s_setprio(0);                                            \
    const float h0_ = fmaxf(q0[0] + fmaf((TV)[0], (TS), (BT)[0]), 0.f);       \
    const float h1_ = fmaxf(q1[0] + fmaf((TV)[1], (TS), (BT)[1]), 0.f);       \
    const float h2_ = fmaxf(q2[0] + fmaf((TV)[2], (TS), (BT)[2]), 0.f);       \
    const float h3_ = fmaxf(q3[0] + fmaf((TV)[3], (TS), (BT)[3]), 0.f);       \
    if (wr) {                                                                 \
      ushort_t* op = (ushort_t*)(OUT);                                        \
      op[64 * w + c]      = CVT16(h0_);                                       \
      op[64 * w + 16 + c] = CVT16(h1_);                                       \
      op[64 * w + 32 + c] = CVT16(h2_);                                       \
      op[64 * w + 48 + c] = CVT16(h3_);                                       \
    }                                                                         \
  }

  // MLP3: L1 Xb->Hb, L2 Hb->Gb, L3 Gb -> (KS0, KS1), valid in all lanes.
#define MLP3(TS)                                                              \
  L128(w1b, b1t, w1tt, (TS), Xb, Hb)                                          \
  bar_lds();                                                                  \
  L128(w2b, b2t, ZV4, 0.f, Hb, Gb)                                            \
  bar_lds();                                                                  \
  {                                                                           \
    const half8* xp = (const half8*)Gb + kg;                                  \
    half8 g0 = xp[0], g1 = xp[4], g2 = xp[8], g3 = xp[12];                    \
    __builtin_amdgcn_s_setprio(1);                                            \
    floatx4 r0 = mfma16(g0, w3b[0][0], zero4);                                \
    floatx4 r1 = mfma16(g0, w3b[1][0], zero4);                                \
    r0 = mfma16(g1, w3b[0][1], r0); r1 = mfma16(g1, w3b[1][1], r1);           \
    r0 = mfma16(g2, w3b[0][2], r0); r1 = mfma16(g2, w3b[1][2], r1);           \
    r0 = mfma16(g3, w3b[0][3], r0); r1 = mfma16(g3, w3b[1][3], r1);           \
    __builtin_amdgcn_s_setprio(0);                                            \
    KS0 = r0[0] + b3r[0];                                                     \
    KS1 = r1[0] + b3r[1];                                                     \
  }

  // Critical-path epilogue: 1 FMA already done by caller; cvt + 4 b16 writes.
#define XWRITE(XV0, XV1, HV0, HV1)             \
  if (wr) {                                    \
    ushort_t* xh = (ushort_t*)Xb;              \
    xh[d0] = CVT16(XV0);                       \
    xh[d1] = CVT16(XV1);                       \
    xh[D + d0] = CVT16(HV0);                   \
    xh[D + d1] = CVT16(HV1);                   \
  }

  for (int n = 0; n < NSTEP; ++n) {
    const float tb = ts0 + (float)n * dt;
    float KS0, KS1;

    // ---- history prefetch for step n+1 (consumed in stage-6 epilogue) ----
    {
      const int m = n + 1;
      const int r0 = (m >= SSEG) ? (m - SSEG) : 0;
      const int r1 = (m >= SSEG) ? (m - SSEG + 1) : 0;
      np00 = r0 ? gme0[(size_t)r0 * D] : y0v0;
      np10 = r1 ? gme0[(size_t)r1 * D] : y0v0;
      np01 = r0 ? gme1[(size_t)r0 * D] : y0v1;
      np11 = r1 ? gme1[(size_t)r1 * D] : y0v1;
    }

    // ---- stage 1: k1 ----
    MLP3(tb)
    kp0 = KS0; kp1 = KS1;
    XWRITE(fmaf(dt * 0.2f, kp0, y_0), fmaf(dt * 0.2f, kp1, y_1),
           fmaf(0.2f, yp10 - yp00, yp00), fmaf(0.2f, yp11 - yp01, yp01))
    bar_lds();

    // ---- stage 2: k2 (top: fold k1 into future partials, off-path) ----
    p30 = fmaf(dt * (3.f / 40.f), kp0, y_0);      p31 = fmaf(dt * (3.f / 40.f), kp1, y_1);
    p40 = fmaf(dt * (44.f / 45.f), kp0, y_0);     p41 = fmaf(dt * (44.f / 45.f), kp1, y_1);
    p50 = fmaf(dt * (19372.f / 6561.f), kp0, y_0); p51 = fmaf(dt * (19372.f / 6561.f), kp1, y_1);
    p60 = fmaf(dt * (9017.f / 3168.f), kp0, y_0);  p61 = fmaf(dt * (9017.f / 3168.f), kp1, y_1);
    py0 = fmaf(dt * (35.f / 384.f), kp0, y_0);     py1 = fmaf(dt * (35.f / 384.f), kp1, y_1);
    MLP3(tb + 0.2f * dt)
    kp0 = KS0; kp1 = KS1;
    XWRITE(fmaf(dt * (9.f / 40.f), kp0, p30), fmaf(dt * (9.f / 40.f), kp1, p31),
           fmaf(0.3f, yp10 - yp00, yp00), fmaf(0.3f, yp11 - yp01, yp01))
    bar_lds();

    // ---- stage 3: k3 ----
    p40 = fmaf(dt * (-56.f / 15.f), kp0, p40);    p41 = fmaf(dt * (-56.f / 15.f), kp1, p41);
    p50 = fmaf(dt * (-25360.f / 2187.f), kp0, p50); p51 = fmaf(dt * (-25360.f / 2187.f), kp1, p51);
    p60 = fmaf(dt * (-355.f / 33.f), kp0, p60);   p61 = fmaf(dt * (-355.f / 33.f), kp1, p61);
    MLP3(tb + 0.3f * dt)
    kp0 = KS0; kp1 = KS1;
    XWRITE(fmaf(dt * (32.f / 9.f), kp0, p40), fmaf(dt * (32.f / 9.f), kp1, p41),
           fmaf(0.8f, yp10 - yp00, yp00), fmaf(0.8f, yp11 - yp01, yp01))
    bar_lds();

    // ---- stage 4: k4 ----
    p50 = fmaf(dt * (64448.f / 6561.f), kp0, p50); p51 = fmaf(dt * (64448.f / 6561.f), kp1, p51);
    p60 = fmaf(dt * (46732.f / 5247.f), kp0, p60); p61 = fmaf(dt * (46732.f / 5247.f), kp1, p61);
    py0 = fmaf(dt * (500.f / 1113.f), kp0, py0);   py1 = fmaf(dt * (500.f / 1113.f), kp1, py1);
    MLP3(tb + 0.8f * dt)
    kp0 = KS0; kp1 = KS1;
    XWRITE(fmaf(dt * (-212.f / 729.f), kp0, p50), fmaf(dt * (-212.f / 729.f), kp1, p51),
           fmaf(8.f / 9.f, yp10 - yp00, yp00), fmaf(8.f / 9.f, yp11 - yp01, yp01))
    bar_lds();

    // ---- stage 5: k5 ----
    p60 = fmaf(dt * (49.f / 176.f), kp0, p60);    p61 = fmaf(dt * (49.f / 176.f), kp1, p61);
    py0 = fmaf(dt * (125.f / 192.f), kp0, py0);   py1 = fmaf(dt * (125.f / 192.f), kp1, py1);
    MLP3(tb + (8.f / 9.f) * dt)
    kp0 = KS0; kp1 = KS1;
    XWRITE(fmaf(dt * (-5103.f / 18656.f), kp0, p60),
           fmaf(dt * (-5103.f / 18656.f), kp1, p61),
           yp10, yp11)  // k6 history is exactly yp1
    bar_lds();

    // ---- stage 6: k6 + y update + dense write + rotate history ----
    py0 = fmaf(dt * (-2187.f / 6784.f), kp0, py0); py1 = fmaf(dt * (-2187.f / 6784.f), kp1, py1);
    MLP3(tb + dt)
    {
      const float yn0 = fmaf(dt * (11.f / 84.f), KS0, py0);
      const float yn1 = fmaf(dt * (11.f / 84.f), KS1, py1);
      y_0 = yn0; y_1 = yn1;
      if (wr) {
        gout[obt + (size_t)(n + 1) * D + d0] = yn0;
        gout[obt + (size_t)(n + 1) * D + d1] = yn1;
      }
      yp00 = np00; yp10 = np10; yp01 = np01; yp11 = np11;
      XWRITE(yn0, yn1, yp00, yp01)  // next step's k1 input
    }
    bar_lds();
  }
#undef MLP3
#undef L128
#undef XWRITE
}

extern "C" void kernel_launch(void* const* d_in, const int* in_sizes, int n_in,
                              void* d_out, int out_size, void* d_ws, size_t ws_size,
                              hipStream_t stream) {
  const float* ts = (const float*)d_in[0];
  const float* y0 = (const float*)d_in[1];
  const float* W1 = (const float*)d_in[2];
  const float* b1 = (const float*)d_in[3];
  const float* W2 = (const float*)d_in[4];
  const float* b2 = (const float*)d_in[5];
  const float* W3 = (const float*)d_in[6];
  const float* b3 = (const float*)d_in[7];
  float* out = (float*)d_out;

  hipLaunchKernelGGL(NeuralDDEWithTime_46823733461186_kernel,
                     dim3(BATCH), dim3(TPB), 0, stream,
                     ts, y0, W1, b1, W2, b2, W3, b3, out);
}